// Round 7
// baseline (1481.767 us; speedup 1.0000x reference)
//
#include <hip/hip_runtime.h>
#include <hip/hip_bf16.h>
#include <cstdint>
#include <cstddef>

// Shapes: B=64, T=512, J=64, D=256, E=128, gdim=8E=1024, gates=4E=512
// ws layout (bytes), total 134,742,016 (~128.5 MiB):
//   [0,           67,108,864)  g as bf16 (32768 x 1024)   -- dead after gemm1
//        aliased: m  bf16 (32768 x 256) at offset 0
//                 m2 bf16 (32768 x 256) at offset 33,554,432
//   [67,108,864, 100,663,296)  pre_f bf16 (32768 x 512)  [cell][gate] layout!
//   [100,663,296,134,217,728)  pre_b bf16 (32768 x 512)  [cell][gate] layout!
//   [134,217,728,...]          gz0, gz1, smax, z  (32768 fp32 each)
// pre layout: pre[row][j*4+q] = gate q (0=i,1=f,2=g,3=o) of cell j.

typedef short short8v __attribute__((ext_vector_type(8)));
typedef float f32x4 __attribute__((ext_vector_type(4)));
typedef unsigned short ushort8v __attribute__((ext_vector_type(8)));
typedef unsigned short ushort4v __attribute__((ext_vector_type(4)));

static __device__ __forceinline__ float bf2f(unsigned short u) {
  return __uint_as_float(((unsigned int)u) << 16);
}
static __device__ __forceinline__ unsigned short f2bf(float f) {  // RNE
  unsigned int u = __float_as_uint(f);
  return (unsigned short)((u + 0x7FFFu + ((u >> 16) & 1u)) >> 16);
}
static __device__ __forceinline__ float fsig(float x) {
  return 1.f / (1.f + __expf(-x));
}
static __device__ __forceinline__ float ftanh(float x) {
  return 1.f - 2.f / (__expf(2.f * x) + 1.f);
}

// ---------------- attention: s, softmax_j, c2q, smax, g[0:768] bf16, gz partial ----
// grid (64, 4)  block 256.  LDS ~133KB -> 1 block/CU.
__global__ __launch_bounds__(256) void attn_kernel(
    const float* __restrict__ c, const float* __restrict__ q,
    const float* __restrict__ wc, const float* __restrict__ bc,
    const float* __restrict__ wq, const float* __restrict__ bq,
    const float* __restrict__ wcq, const float* __restrict__ bcq,
    const float* __restrict__ W0, const float* __restrict__ W1,
    __hip_bfloat16* __restrict__ g, float* __restrict__ smax,
    float* __restrict__ gz0, float* __restrict__ gz1)
{
  __shared__ float qr[64][256];    // j-major (c2q: lanes sweep d, conflict-free)
  __shared__ float qrt[256][64];   // d-major (s-dot: lanes sweep j, conflict-free)
  __shared__ float qwqs[64];
  __shared__ float cwbuf[4][256];  // per-wave c*wcq row (wave-private)
  __shared__ float abuf[4][64];    // per-wave attention weights (wave-private)
  const int b = blockIdx.x;
  const int tid = threadIdx.x;
  for (int e = tid; e < 64 * 256; e += 256) {
    int j = e >> 8, d = e & 255;
    float v = q[((size_t)b * 64 + j) * 256 + d];
    qr[j][d] = v;
    qrt[d][j] = v;
  }
  __syncthreads();
  if (tid < 64) {
    float s = 0.f;
    for (int d = 0; d < 256; ++d) s += qrt[d][tid] * wq[d];
    qwqs[tid] = s + bq[0];
  }
  __syncthreads();
  const int wave = tid >> 6, lane = tid & 63;
  const float bcv = bc[0], bcqv = bcq[0];
  const int t0 = blockIdx.y * 128;
  for (int it = 0; it < 32; ++it) {
    const int trow = t0 + wave + it * 4;
    const float* crow = c + ((size_t)b * 512 + trow) * 256;
    float cv[4];
    float part = 0.f;
    #pragma unroll
    for (int r = 0; r < 4; ++r) {
      int d = lane + 64 * r;
      cv[r] = crow[d];
      cwbuf[wave][d] = cv[r] * wcq[d];
      part += cv[r] * wc[d];
    }
    #pragma unroll
    for (int off = 32; off; off >>= 1) part += __shfl_xor(part, off);
    float s = part + bcv + qwqs[lane] + bcqv;   // lane == j
    #pragma unroll 8
    for (int d = 0; d < 256; ++d) s += cwbuf[wave][d] * qrt[d][lane];
    float mx = s;
    #pragma unroll
    for (int off = 32; off; off >>= 1) mx = fmaxf(mx, __shfl_xor(mx, off));
    float e = expf(s - mx);
    float sum = e;
    #pragma unroll
    for (int off = 32; off; off >>= 1) sum += __shfl_xor(sum, off);
    abuf[wave][lane] = e / sum;
    const size_t grow = (size_t)b * 512 + trow;
    if (lane == 0) smax[grow] = mx;
    size_t row = grow * 1024;
    float az0 = 0.f, az1 = 0.f;
    #pragma unroll
    for (int r = 0; r < 4; ++r) {
      int d = lane + 64 * r;
      float acc = 0.f;
      #pragma unroll 8
      for (int j = 0; j < 64; ++j) acc += abuf[wave][j] * qr[j][d];
      float prod = cv[r] * acc;
      g[row + d]       = __float2bfloat16(cv[r]);
      g[row + 256 + d] = __float2bfloat16(acc);
      g[row + 512 + d] = __float2bfloat16(prod);
      az0 += cv[r] * W0[d] + acc * W0[256 + d] + prod * W0[512 + d];
      az1 += cv[r] * W1[d] + acc * W1[256 + d] + prod * W1[512 + d];
    }
    #pragma unroll
    for (int off = 32; off; off >>= 1) {
      az0 += __shfl_xor(az0, off);
      az1 += __shfl_xor(az1, off);
    }
    if (lane == 0) { gz0[grow] = az0; gz1[grow] = az1; }
  }
}

// ---------------- b_att softmax over t, q2c, g[768:1024] bf16, gz tail ----------
// grid 64, block 256
__global__ __launch_bounds__(256) void batt_kernel(
    const float* __restrict__ c, const float* __restrict__ smax,
    const float* __restrict__ W0, const float* __restrict__ W1,
    __hip_bfloat16* __restrict__ g,
    float* __restrict__ gz0, float* __restrict__ gz1)
{
  __shared__ float sm[512];
  __shared__ float red[4], red2[4];
  __shared__ float q2c_s[256];
  const int b = blockIdx.x, tid = threadIdx.x;
  float v0 = smax[(size_t)b * 512 + tid];
  float v1 = smax[(size_t)b * 512 + tid + 256];
  float m = fmaxf(v0, v1);
  #pragma unroll
  for (int off = 32; off; off >>= 1) m = fmaxf(m, __shfl_xor(m, off));
  if ((tid & 63) == 0) red[tid >> 6] = m;
  __syncthreads();
  float M = fmaxf(fmaxf(red[0], red[1]), fmaxf(red[2], red[3]));
  float e0 = expf(v0 - M), e1 = expf(v1 - M);
  float ssum = e0 + e1;
  #pragma unroll
  for (int off = 32; off; off >>= 1) ssum += __shfl_xor(ssum, off);
  if ((tid & 63) == 0) red2[tid >> 6] = ssum;
  __syncthreads();
  float S = red2[0] + red2[1] + red2[2] + red2[3];
  sm[tid] = e0 / S;
  sm[tid + 256] = e1 / S;
  __syncthreads();
  float acc = 0.f;
  #pragma unroll 8
  for (int t = 0; t < 512; ++t) acc += sm[t] * c[((size_t)b * 512 + t) * 256 + tid];
  q2c_s[tid] = acc;
  __syncthreads();
  const int wave = tid >> 6, lane = tid & 63;
  float qv[4], w0c[4], w1c[4];
  #pragma unroll
  for (int r = 0; r < 4; ++r) {
    int d = lane + 64 * r;
    qv[r]  = q2c_s[d];
    w0c[r] = W0[768 + d];
    w1c[r] = W1[768 + d];
  }
  for (int t = wave; t < 512; t += 4) {
    size_t row = (size_t)b * 512 + t;
    float s0 = 0.f, s1 = 0.f;
    #pragma unroll
    for (int r = 0; r < 4; ++r) {
      int d = lane + 64 * r;
      float v = c[row * 256 + d];
      float gv = v * qv[r];
      g[row * 1024 + 768 + d] = __float2bfloat16(gv);
      s0 += gv * w0c[r];
      s1 += gv * w1c[r];
    }
    #pragma unroll
    for (int off = 32; off; off >>= 1) {
      s0 += __shfl_xor(s0, off);
      s1 += __shfl_xor(s1, off);
    }
    if (lane == 0) { gz0[row] += s0; gz1[row] += s1; }
  }
}

// ---------------- MFMA GEMM: pre[M,512] = Xbf16[M,K] @ Wfp32[512,K]^T + b1 + b2 ---
// grid (M/128, 4), block 256 (4 waves, each 64x64). BK=64. W cvt'd inline.
// Output stored PERMUTED: pre[row][ (col&127)*4 + (col>>7) ]  ([cell][gate]).
__global__ __launch_bounds__(256) void gemm_mfma_kernel(
    const __hip_bfloat16* __restrict__ Xg, const float* __restrict__ W,
    const float* __restrict__ bias1, const float* __restrict__ bias2,
    __hip_bfloat16* __restrict__ Y, int K, int N)
{
  __shared__ unsigned short Xs[128 * 72];  // row stride 72 (+8 pad = 16B, b128-aligned)
  __shared__ unsigned short Ws[128 * 72];
  const unsigned short* X = (const unsigned short*)Xg;
  const int tid = threadIdx.x;
  const int m0 = blockIdx.x * 128, n0 = blockIdx.y * 128;
  const int lane = tid & 63, wave = tid >> 6;
  const int wr = wave >> 1, wc = wave & 1;
  const int frow = lane & 15, fk = (lane >> 4) * 8;

  f32x4 acc[4][4] = {};
  for (int kt = 0; kt < K; kt += 64) {
    #pragma unroll
    for (int i = 0; i < 4; ++i) {
      int cidx = tid + 256 * i;          // 0..1023
      int row = cidx >> 3, kc = cidx & 7;
      ushort8v v = *(const ushort8v*)&X[(size_t)(m0 + row) * K + kt + kc * 8];
      *(ushort8v*)&Xs[row * 72 + kc * 8] = v;
    }
    #pragma unroll
    for (int i = 0; i < 4; ++i) {
      int cidx = tid + 256 * i;
      int row = cidx >> 3, kc = cidx & 7;
      const float* wp = &W[(size_t)(n0 + row) * K + kt + kc * 8];
      float4 f0 = *(const float4*)wp;
      float4 f1 = *(const float4*)(wp + 4);
      ushort8v v;
      v[0] = f2bf(f0.x); v[1] = f2bf(f0.y); v[2] = f2bf(f0.z); v[3] = f2bf(f0.w);
      v[4] = f2bf(f1.x); v[5] = f2bf(f1.y); v[6] = f2bf(f1.z); v[7] = f2bf(f1.w);
      *(ushort8v*)&Ws[row * 72 + kc * 8] = v;
    }
    __syncthreads();
    #pragma unroll
    for (int kk = 0; kk < 64; kk += 32) {
      short8v a[4], bfr[4];
      #pragma unroll
      for (int i = 0; i < 4; ++i)
        a[i] = *(const short8v*)&Xs[(wr * 64 + i * 16 + frow) * 72 + kk + fk];
      #pragma unroll
      for (int j = 0; j < 4; ++j)
        bfr[j] = *(const short8v*)&Ws[(wc * 64 + j * 16 + frow) * 72 + kk + fk];
      #pragma unroll
      for (int i = 0; i < 4; ++i)
        #pragma unroll
        for (int j = 0; j < 4; ++j)
          acc[i][j] = __builtin_amdgcn_mfma_f32_16x16x32_bf16(a[i], bfr[j], acc[i][j], 0, 0, 0);
    }
    __syncthreads();
  }
  const int r0 = (lane >> 4) * 4;
  #pragma unroll
  for (int j = 0; j < 4; ++j) {
    int col = n0 + wc * 64 + j * 16 + (lane & 15);
    int colp = (col & 127) * 4 + (col >> 7);   // [cell][gate] permuted layout
    float bsum = bias1[col] + bias2[col];
    #pragma unroll
    for (int i = 0; i < 4; ++i) {
      int rowb = m0 + wr * 64 + i * 16 + r0;
      #pragma unroll
      for (int r = 0; r < 4; ++r)
        Y[(size_t)(rowb + r) * N + colp] = __float2bfloat16(acc[i][j][r] + bsum);
    }
  }
}

// ---------------- LSTM recurrence via MFMA ----------------
// grid (64, 2) block 512 (8 waves). Per step: gates[512] = Whh·h via
// mfma_f32_16x16x32_bf16 with A = h broadcast into all 16 rows.
// B = Whh bf16 fragments resident in VGPRs (asm-pinned).
// KEY (r7): raw s_barrier + lgkmcnt(0)-only drain. __syncthreads() would emit
// s_waitcnt vmcnt(0) and drain the pre prefetch every step (~900cy stall, the
// r6 bottleneck). Only the LDS h-write needs draining; pre loads stay in
// flight across the barrier (AITER's counted-vmcnt discipline). Prefetch
// depth 2 gives each pre load ~2 steps of slack >= HBM latency.
__global__ __launch_bounds__(512, 2) void lstm_kernel(
    const __hip_bfloat16* __restrict__ pre_f, const __hip_bfloat16* __restrict__ pre_b,
    const float* __restrict__ Whh_f, const float* __restrict__ Whh_b,
    __hip_bfloat16* __restrict__ out)
{
  const int b = blockIdx.x, dir = blockIdx.y;
  const unsigned short* __restrict__ pre =
      (const unsigned short*)(dir ? pre_b : pre_f);
  const float* __restrict__ Whh = dir ? Whh_b : Whh_f;
  const int off = dir ? 128 : 0;
  const int tid = threadIdx.x;
  const int wave = tid >> 6, lane = tid & 63;
  const int cl = lane & 15;            // col / cell-within-wave
  const int kg = lane >> 4;            // k-group 0..3
  const int cell = wave * 16 + cl;     // 0..127

  // B fragments: bf[q][kt] = Whh[q*128+cell][kt*32 + kg*8 .. +8] as bf16
  short8v bf[4][4];
  #pragma unroll
  for (int q = 0; q < 4; ++q) {
    const float* wrow = Whh + (size_t)(q * 128 + cell) * 128;
    #pragma unroll
    for (int kt = 0; kt < 4; ++kt) {
      const float* wp = wrow + kt * 32 + kg * 8;
      float4 f0 = *(const float4*)wp;
      float4 f1 = *(const float4*)(wp + 4);
      short8v v;
      v[0] = (short)f2bf(f0.x); v[1] = (short)f2bf(f0.y);
      v[2] = (short)f2bf(f0.z); v[3] = (short)f2bf(f0.w);
      v[4] = (short)f2bf(f1.x); v[5] = (short)f2bf(f1.y);
      v[6] = (short)f2bf(f1.z); v[7] = (short)f2bf(f1.w);
      bf[q][kt] = v;
      asm volatile("" : "+v"(bf[q][kt]));   // pin: forbid remat/spill-to-reload
    }
  }

  __shared__ unsigned short hbuf[2][128];   // h as bf16, double-buffered
  if (tid < 128) { hbuf[0][tid] = 0; hbuf[1][tid] = 0; }
  __syncthreads();

  const size_t base = (size_t)b * 512;
  int t = dir ? 511 : 0;
  const int tstep = dir ? -1 : 1;
  ushort4v p_cur = *(const ushort4v*)(pre + (base + t) * 512 + cell * 4);
  ushort4v p_nx  = *(const ushort4v*)(pre + (base + t + tstep) * 512 + cell * 4);
  int cur = 0;
  float cst = 0.f;
  for (int s = 0; s < 512; ++s) {
    ushort4v p_nx2 = p_nx;
    if (s < 510)
      p_nx2 = *(const ushort4v*)(pre + (base + t + 2 * tstep) * 512 + cell * 4);
    // A fragments: each 16-lane group reads the same 16B of h -> broadcast
    const unsigned short* hb = hbuf[cur];
    short8v a0 = *(const short8v*)(hb +  0 + kg * 8);
    short8v a1 = *(const short8v*)(hb + 32 + kg * 8);
    short8v a2 = *(const short8v*)(hb + 64 + kg * 8);
    short8v a3 = *(const short8v*)(hb + 96 + kg * 8);
    f32x4 acc[4];
    #pragma unroll
    for (int q = 0; q < 4; ++q) {
      float pv = bf2f(p_cur[q]);
      acc[q] = (f32x4){pv, pv, pv, pv};
      acc[q] = __builtin_amdgcn_mfma_f32_16x16x32_bf16(a0, bf[q][0], acc[q], 0, 0, 0);
      acc[q] = __builtin_amdgcn_mfma_f32_16x16x32_bf16(a1, bf[q][1], acc[q], 0, 0, 0);
      acc[q] = __builtin_amdgcn_mfma_f32_16x16x32_bf16(a2, bf[q][2], acc[q], 0, 0, 0);
      acc[q] = __builtin_amdgcn_mfma_f32_16x16x32_bf16(a3, bf[q][3], acc[q], 0, 0, 0);
    }
    float gi_ = fsig(acc[0][0]);
    float gf_ = fsig(acc[1][0]);
    float gg_ = ftanh(acc[2][0]);
    float go_ = fsig(acc[3][0]);
    cst = gf_ * cst + gi_ * gg_;          // replicated across the 4 k-groups
    float hv = go_ * ftanh(cst);
    if (lane < 16) {
      hbuf[cur ^ 1][cell] = f2bf(hv);
      out[(base + t) * 256 + off + cell] = __float2bfloat16(hv);
    }
    // Drain ONLY LDS (h-write visibility); pre loads stay in flight (vmcnt>0).
    asm volatile("s_waitcnt lgkmcnt(0)" ::: "memory");
    __builtin_amdgcn_sched_barrier(0);
    __builtin_amdgcn_s_barrier();
    __builtin_amdgcn_sched_barrier(0);
    p_cur = p_nx;
    p_nx = p_nx2;
    t += tstep;
    cur ^= 1;
  }
}

// ---------------- logits: z[row] = gz[row] + m_row(bf16) . W[1024:1280] + bias ----
// grid 8192, block 256 (wave per row)
__global__ __launch_bounds__(256) void logits_kernel(
    const __hip_bfloat16* __restrict__ m, const float* __restrict__ W,
    const float* __restrict__ bias, const float* __restrict__ gz,
    float* __restrict__ z)
{
  const int row = blockIdx.x * 4 + (threadIdx.x >> 6);
  const int lane = threadIdx.x & 63;
  const unsigned short* mrow = (const unsigned short*)m + (size_t)row * 256;
  float acc = 0.f;
  #pragma unroll
  for (int i = 0; i < 4; ++i) acc += bf2f(mrow[lane + 64 * i]) * W[1024 + lane + 64 * i];
  #pragma unroll
  for (int off = 32; off; off >>= 1) acc += __shfl_xor(acc, off);
  if (lane == 0) z[row] = acc + gz[row] + bias[0];
}

// ---------------- softmax over t ----------------
// grid 64, block 512
__global__ __launch_bounds__(512) void softmax_t_kernel(
    const float* __restrict__ z, float* __restrict__ p)
{
  const int b = blockIdx.x, t = threadIdx.x;
  __shared__ float red[8], red2[8];
  float v = z[(size_t)b * 512 + t];
  float m = v;
  #pragma unroll
  for (int off = 32; off; off >>= 1) m = fmaxf(m, __shfl_xor(m, off));
  if ((t & 63) == 0) red[t >> 6] = m;
  __syncthreads();
  float M = red[0];
  #pragma unroll
  for (int i = 1; i < 8; ++i) M = fmaxf(M, red[i]);
  float e = expf(v - M);
  float s = e;
  #pragma unroll
  for (int off = 32; off; off >>= 1) s += __shfl_xor(s, off);
  if ((t & 63) == 0) red2[t >> 6] = s;
  __syncthreads();
  float S = red2[0];
  #pragma unroll
  for (int i = 1; i < 8; ++i) S += red2[i];
  p[(size_t)b * 512 + t] = e / S;
}

extern "C" void kernel_launch(void* const* d_in, const int* in_sizes, int n_in,
                              void* d_out, int out_size, void* d_ws, size_t ws_size,
                              hipStream_t stream)
{
  const float* c   = (const float*)d_in[0];
  const float* q   = (const float*)d_in[1];
  const float* wc  = (const float*)d_in[2];
  const float* bc  = (const float*)d_in[3];
  const float* wq  = (const float*)d_in[4];
  const float* bq  = (const float*)d_in[5];
  const float* wcq = (const float*)d_in[6];
  const float* bcq = (const float*)d_in[7];
  const float* l1f_Wih = (const float*)d_in[8];
  const float* l1f_Whh = (const float*)d_in[9];
  const float* l1f_bih = (const float*)d_in[10];
  const float* l1f_bhh = (const float*)d_in[11];
  const float* l1b_Wih = (const float*)d_in[12];
  const float* l1b_Whh = (const float*)d_in[13];
  const float* l1b_bih = (const float*)d_in[14];
  const float* l1b_bhh = (const float*)d_in[15];
  const float* l2f_Wih = (const float*)d_in[16];
  const float* l2f_Whh = (const float*)d_in[17];
  const float* l2f_bih = (const float*)d_in[18];
  const float* l2f_bhh = (const float*)d_in[19];
  const float* l2b_Wih = (const float*)d_in[20];
  const float* l2b_Whh = (const float*)d_in[21];
  const float* l2b_bih = (const float*)d_in[22];
  const float* l2b_bhh = (const float*)d_in[23];
  const float* W0 = (const float*)d_in[24];
  const float* b0 = (const float*)d_in[25];
  const float* W1 = (const float*)d_in[26];
  const float* b1 = (const float*)d_in[27];

  const size_t required = 134742016u;
  if (ws_size < required) return;

  char* wsb = (char*)d_ws;
  __hip_bfloat16* gbf = (__hip_bfloat16*)wsb;                  // 67,108,864 B
  __hip_bfloat16* m   = (__hip_bfloat16*)wsb;                  // alias (g dead after gemm1)
  __hip_bfloat16* m2  = (__hip_bfloat16*)(wsb + 33554432);     // alias
  __hip_bfloat16* pref = (__hip_bfloat16*)(wsb + 67108864);    // 33,554,432 B
  __hip_bfloat16* preb = (__hip_bfloat16*)(wsb + 100663296);   // 33,554,432 B
  float* gz0  = (float*)(wsb + 134217728);
  float* gz1  = gz0 + 32768;
  float* smax = gz1 + 32768;
  float* z    = smax + 32768;
  float* p1   = (float*)d_out;
  float* p2   = p1 + 32768;

  attn_kernel<<<dim3(64, 4), 256, 0, stream>>>(c, q, wc, bc, wq, bq, wcq, bcq,
                                               W0, W1, gbf, smax, gz0, gz1);
  batt_kernel<<<64, 256, 0, stream>>>(c, smax, W0, W1, gbf, gz0, gz1);

  gemm_mfma_kernel<<<dim3(256, 4), 256, 0, stream>>>(gbf, l1f_Wih, l1f_bih, l1f_bhh, pref, 1024, 512);
  gemm_mfma_kernel<<<dim3(256, 4), 256, 0, stream>>>(gbf, l1b_Wih, l1b_bih, l1b_bhh, preb, 1024, 512);
  lstm_kernel<<<dim3(64, 2), 512, 0, stream>>>(pref, preb, l1f_Whh, l1b_Whh, m);

  logits_kernel<<<8192, 256, 0, stream>>>(m, W0, b0, gz0, z);
  softmax_t_kernel<<<64, 512, 0, stream>>>(z, p1);

  gemm_mfma_kernel<<<dim3(256, 4), 256, 0, stream>>>(m, l2f_Wih, l2f_bih, l2f_bhh, pref, 256, 512);
  gemm_mfma_kernel<<<dim3(256, 4), 256, 0, stream>>>(m, l2b_Wih, l2b_bih, l2b_bhh, preb, 256, 512);
  lstm_kernel<<<dim3(64, 2), 512, 0, stream>>>(pref, preb, l2f_Whh, l2b_Whh, m2);

  logits_kernel<<<8192, 256, 0, stream>>>(m2, W1, b1, gz1, z);
  softmax_t_kernel<<<64, 512, 0, stream>>>(z, p2);
}

// Round 8
// 1215.949 us; speedup vs baseline: 1.2186x; 1.2186x over previous
//
#include <hip/hip_runtime.h>
#include <hip/hip_bf16.h>
#include <cstdint>
#include <cstddef>

// Shapes: B=64, T=512, J=64, D=256, E=128, gdim=8E=1024, gates=4E=512
// ws layout (bytes), total 134,742,016 (~128.5 MiB):
//   [0,           67,108,864)  g as bf16 (32768 x 1024)   -- dead after gemm1
//        aliased: m  bf16 (32768 x 256) at offset 0
//                 m2 bf16 (32768 x 256) at offset 33,554,432
//   [67,108,864, 100,663,296)  pre_f bf16 (32768 x 512)  [cell][gate] layout!
//   [100,663,296,134,217,728)  pre_b bf16 (32768 x 512)  [cell][gate] layout!
//   [134,217,728,...]          gz0, gz1, smax, z  (32768 fp32 each)
// pre layout: pre[row][j*4+q] = gate q (0=i,1=f,2=g,3=o) of cell j.

typedef short short8v __attribute__((ext_vector_type(8)));
typedef float f32x4 __attribute__((ext_vector_type(4)));
typedef unsigned short ushort8v __attribute__((ext_vector_type(8)));
typedef unsigned short ushort4v __attribute__((ext_vector_type(4)));

static __device__ __forceinline__ float bf2f(unsigned short u) {
  return __uint_as_float(((unsigned int)u) << 16);
}
static __device__ __forceinline__ unsigned short f2bf(float f) {  // RNE
  unsigned int u = __float_as_uint(f);
  return (unsigned short)((u + 0x7FFFu + ((u >> 16) & 1u)) >> 16);
}
static __device__ __forceinline__ float fsig(float x) {
  return 1.f / (1.f + __expf(-x));
}
static __device__ __forceinline__ float ftanh(float x) {
  return 1.f - 2.f / (__expf(2.f * x) + 1.f);
}

// ---------------- attention: s, softmax_j, c2q, smax, g[0:768] bf16, gz partial ----
// grid (64, 4)  block 256.  LDS ~133KB -> 1 block/CU.
__global__ __launch_bounds__(256) void attn_kernel(
    const float* __restrict__ c, const float* __restrict__ q,
    const float* __restrict__ wc, const float* __restrict__ bc,
    const float* __restrict__ wq, const float* __restrict__ bq,
    const float* __restrict__ wcq, const float* __restrict__ bcq,
    const float* __restrict__ W0, const float* __restrict__ W1,
    __hip_bfloat16* __restrict__ g, float* __restrict__ smax,
    float* __restrict__ gz0, float* __restrict__ gz1)
{
  __shared__ float qr[64][256];    // j-major (c2q: lanes sweep d, conflict-free)
  __shared__ float qrt[256][64];   // d-major (s-dot: lanes sweep j, conflict-free)
  __shared__ float qwqs[64];
  __shared__ float cwbuf[4][256];  // per-wave c*wcq row (wave-private)
  __shared__ float abuf[4][64];    // per-wave attention weights (wave-private)
  const int b = blockIdx.x;
  const int tid = threadIdx.x;
  for (int e = tid; e < 64 * 256; e += 256) {
    int j = e >> 8, d = e & 255;
    float v = q[((size_t)b * 64 + j) * 256 + d];
    qr[j][d] = v;
    qrt[d][j] = v;
  }
  __syncthreads();
  if (tid < 64) {
    float s = 0.f;
    for (int d = 0; d < 256; ++d) s += qrt[d][tid] * wq[d];
    qwqs[tid] = s + bq[0];
  }
  __syncthreads();
  const int wave = tid >> 6, lane = tid & 63;
  const float bcv = bc[0], bcqv = bcq[0];
  const int t0 = blockIdx.y * 128;
  for (int it = 0; it < 32; ++it) {
    const int trow = t0 + wave + it * 4;
    const float* crow = c + ((size_t)b * 512 + trow) * 256;
    float cv[4];
    float part = 0.f;
    #pragma unroll
    for (int r = 0; r < 4; ++r) {
      int d = lane + 64 * r;
      cv[r] = crow[d];
      cwbuf[wave][d] = cv[r] * wcq[d];
      part += cv[r] * wc[d];
    }
    #pragma unroll
    for (int off = 32; off; off >>= 1) part += __shfl_xor(part, off);
    float s = part + bcv + qwqs[lane] + bcqv;   // lane == j
    #pragma unroll 8
    for (int d = 0; d < 256; ++d) s += cwbuf[wave][d] * qrt[d][lane];
    float mx = s;
    #pragma unroll
    for (int off = 32; off; off >>= 1) mx = fmaxf(mx, __shfl_xor(mx, off));
    float e = expf(s - mx);
    float sum = e;
    #pragma unroll
    for (int off = 32; off; off >>= 1) sum += __shfl_xor(sum, off);
    abuf[wave][lane] = e / sum;
    const size_t grow = (size_t)b * 512 + trow;
    if (lane == 0) smax[grow] = mx;
    size_t row = grow * 1024;
    float az0 = 0.f, az1 = 0.f;
    #pragma unroll
    for (int r = 0; r < 4; ++r) {
      int d = lane + 64 * r;
      float acc = 0.f;
      #pragma unroll 8
      for (int j = 0; j < 64; ++j) acc += abuf[wave][j] * qr[j][d];
      float prod = cv[r] * acc;
      g[row + d]       = __float2bfloat16(cv[r]);
      g[row + 256 + d] = __float2bfloat16(acc);
      g[row + 512 + d] = __float2bfloat16(prod);
      az0 += cv[r] * W0[d] + acc * W0[256 + d] + prod * W0[512 + d];
      az1 += cv[r] * W1[d] + acc * W1[256 + d] + prod * W1[512 + d];
    }
    #pragma unroll
    for (int off = 32; off; off >>= 1) {
      az0 += __shfl_xor(az0, off);
      az1 += __shfl_xor(az1, off);
    }
    if (lane == 0) { gz0[grow] = az0; gz1[grow] = az1; }
  }
}

// ---------------- b_att softmax over t, q2c, g[768:1024] bf16, gz tail ----------
// grid 64, block 256
__global__ __launch_bounds__(256) void batt_kernel(
    const float* __restrict__ c, const float* __restrict__ smax,
    const float* __restrict__ W0, const float* __restrict__ W1,
    __hip_bfloat16* __restrict__ g,
    float* __restrict__ gz0, float* __restrict__ gz1)
{
  __shared__ float sm[512];
  __shared__ float red[4], red2[4];
  __shared__ float q2c_s[256];
  const int b = blockIdx.x, tid = threadIdx.x;
  float v0 = smax[(size_t)b * 512 + tid];
  float v1 = smax[(size_t)b * 512 + tid + 256];
  float m = fmaxf(v0, v1);
  #pragma unroll
  for (int off = 32; off; off >>= 1) m = fmaxf(m, __shfl_xor(m, off));
  if ((tid & 63) == 0) red[tid >> 6] = m;
  __syncthreads();
  float M = fmaxf(fmaxf(red[0], red[1]), fmaxf(red[2], red[3]));
  float e0 = expf(v0 - M), e1 = expf(v1 - M);
  float ssum = e0 + e1;
  #pragma unroll
  for (int off = 32; off; off >>= 1) ssum += __shfl_xor(ssum, off);
  if ((tid & 63) == 0) red2[tid >> 6] = ssum;
  __syncthreads();
  float S = red2[0] + red2[1] + red2[2] + red2[3];
  sm[tid] = e0 / S;
  sm[tid + 256] = e1 / S;
  __syncthreads();
  float acc = 0.f;
  #pragma unroll 8
  for (int t = 0; t < 512; ++t) acc += sm[t] * c[((size_t)b * 512 + t) * 256 + tid];
  q2c_s[tid] = acc;
  __syncthreads();
  const int wave = tid >> 6, lane = tid & 63;
  float qv[4], w0c[4], w1c[4];
  #pragma unroll
  for (int r = 0; r < 4; ++r) {
    int d = lane + 64 * r;
    qv[r]  = q2c_s[d];
    w0c[r] = W0[768 + d];
    w1c[r] = W1[768 + d];
  }
  for (int t = wave; t < 512; t += 4) {
    size_t row = (size_t)b * 512 + t;
    float s0 = 0.f, s1 = 0.f;
    #pragma unroll
    for (int r = 0; r < 4; ++r) {
      int d = lane + 64 * r;
      float v = c[row * 256 + d];
      float gv = v * qv[r];
      g[row * 1024 + 768 + d] = __float2bfloat16(gv);
      s0 += gv * w0c[r];
      s1 += gv * w1c[r];
    }
    #pragma unroll
    for (int off = 32; off; off >>= 1) {
      s0 += __shfl_xor(s0, off);
      s1 += __shfl_xor(s1, off);
    }
    if (lane == 0) { gz0[row] += s0; gz1[row] += s1; }
  }
}

// ---------------- MFMA GEMM: pre[M,512] = Xbf16[M,K] @ Wfp32[512,K]^T + b1 + b2 ---
// grid (M/128, 4), block 256 (4 waves, each 64x64). BK=64. W cvt'd inline.
// Output stored PERMUTED: pre[row][ (col&127)*4 + (col>>7) ]  ([cell][gate]).
__global__ __launch_bounds__(256) void gemm_mfma_kernel(
    const __hip_bfloat16* __restrict__ Xg, const float* __restrict__ W,
    const float* __restrict__ bias1, const float* __restrict__ bias2,
    __hip_bfloat16* __restrict__ Y, int K, int N)
{
  __shared__ unsigned short Xs[128 * 72];  // row stride 72 (+8 pad = 16B, b128-aligned)
  __shared__ unsigned short Ws[128 * 72];
  const unsigned short* X = (const unsigned short*)Xg;
  const int tid = threadIdx.x;
  const int m0 = blockIdx.x * 128, n0 = blockIdx.y * 128;
  const int lane = tid & 63, wave = tid >> 6;
  const int wr = wave >> 1, wc = wave & 1;
  const int frow = lane & 15, fk = (lane >> 4) * 8;

  f32x4 acc[4][4] = {};
  for (int kt = 0; kt < K; kt += 64) {
    #pragma unroll
    for (int i = 0; i < 4; ++i) {
      int cidx = tid + 256 * i;          // 0..1023
      int row = cidx >> 3, kc = cidx & 7;
      ushort8v v = *(const ushort8v*)&X[(size_t)(m0 + row) * K + kt + kc * 8];
      *(ushort8v*)&Xs[row * 72 + kc * 8] = v;
    }
    #pragma unroll
    for (int i = 0; i < 4; ++i) {
      int cidx = tid + 256 * i;
      int row = cidx >> 3, kc = cidx & 7;
      const float* wp = &W[(size_t)(n0 + row) * K + kt + kc * 8];
      float4 f0 = *(const float4*)wp;
      float4 f1 = *(const float4*)(wp + 4);
      ushort8v v;
      v[0] = f2bf(f0.x); v[1] = f2bf(f0.y); v[2] = f2bf(f0.z); v[3] = f2bf(f0.w);
      v[4] = f2bf(f1.x); v[5] = f2bf(f1.y); v[6] = f2bf(f1.z); v[7] = f2bf(f1.w);
      *(ushort8v*)&Ws[row * 72 + kc * 8] = v;
    }
    __syncthreads();
    #pragma unroll
    for (int kk = 0; kk < 64; kk += 32) {
      short8v a[4], bfr[4];
      #pragma unroll
      for (int i = 0; i < 4; ++i)
        a[i] = *(const short8v*)&Xs[(wr * 64 + i * 16 + frow) * 72 + kk + fk];
      #pragma unroll
      for (int j = 0; j < 4; ++j)
        bfr[j] = *(const short8v*)&Ws[(wc * 64 + j * 16 + frow) * 72 + kk + fk];
      #pragma unroll
      for (int i = 0; i < 4; ++i)
        #pragma unroll
        for (int j = 0; j < 4; ++j)
          acc[i][j] = __builtin_amdgcn_mfma_f32_16x16x32_bf16(a[i], bfr[j], acc[i][j], 0, 0, 0);
    }
    __syncthreads();
  }
  const int r0 = (lane >> 4) * 4;
  #pragma unroll
  for (int j = 0; j < 4; ++j) {
    int col = n0 + wc * 64 + j * 16 + (lane & 15);
    int colp = (col & 127) * 4 + (col >> 7);   // [cell][gate] permuted layout
    float bsum = bias1[col] + bias2[col];
    #pragma unroll
    for (int i = 0; i < 4; ++i) {
      int rowb = m0 + wr * 64 + i * 16 + r0;
      #pragma unroll
      for (int r = 0; r < 4; ++r)
        Y[(size_t)(rowb + r) * N + colp] = __float2bfloat16(acc[i][j][r] + bsum);
    }
  }
}

// ---------------- LSTM recurrence via MFMA, 8-step chunked I/O ----------------
// grid (64, 2) block 512 (8 waves). Per step per wave: 4 ds_read_b128 (h bcast)
// + 16 MFMA + activations; __syncthreads per step (r7 showed raw-barrier +
// sched_barrier is WORSE). VMEM is chunked: 8 steps of pre loaded into regs at
// chunk top (drained once by step-0's sync), h outputs buffered in regs and
// stored once per chunk -> steps 1-7 have no VMEM pending at their barrier.
// acc rows 1-3 hold never-read garbage (no per-step zero-init; saves 12 movs).
__global__ __launch_bounds__(512, 2) void lstm_kernel(
    const __hip_bfloat16* __restrict__ pre_f, const __hip_bfloat16* __restrict__ pre_b,
    const float* __restrict__ Whh_f, const float* __restrict__ Whh_b,
    __hip_bfloat16* __restrict__ out)
{
  const int b = blockIdx.x, dir = blockIdx.y;
  const unsigned short* __restrict__ pre =
      (const unsigned short*)(dir ? pre_b : pre_f);
  const float* __restrict__ Whh = dir ? Whh_b : Whh_f;
  const int off = dir ? 128 : 0;
  const int tid = threadIdx.x;
  const int wave = tid >> 6, lane = tid & 63;
  const int cl = lane & 15;            // col / cell-within-wave
  const int kg = lane >> 4;            // k-group 0..3
  const int cell = wave * 16 + cl;     // 0..127

  // B fragments (16 named vars): bfQ_T = Whh[q*128+cell][kt*32 + kg*8 .. +8]
#define LOAD_BF(Q, T, DST)                                            \
  {                                                                   \
    const float* wp = Whh + (size_t)(Q * 128 + cell) * 128 + T * 32 + kg * 8; \
    float4 f0 = *(const float4*)wp;                                   \
    float4 f1 = *(const float4*)(wp + 4);                             \
    DST[0] = (short)f2bf(f0.x); DST[1] = (short)f2bf(f0.y);           \
    DST[2] = (short)f2bf(f0.z); DST[3] = (short)f2bf(f0.w);           \
    DST[4] = (short)f2bf(f1.x); DST[5] = (short)f2bf(f1.y);           \
    DST[6] = (short)f2bf(f1.z); DST[7] = (short)f2bf(f1.w);           \
    asm volatile("" : "+v"(DST));                                     \
  }
  short8v bf00, bf01, bf02, bf03, bf10, bf11, bf12, bf13;
  short8v bf20, bf21, bf22, bf23, bf30, bf31, bf32, bf33;
  LOAD_BF(0, 0, bf00) LOAD_BF(0, 1, bf01) LOAD_BF(0, 2, bf02) LOAD_BF(0, 3, bf03)
  LOAD_BF(1, 0, bf10) LOAD_BF(1, 1, bf11) LOAD_BF(1, 2, bf12) LOAD_BF(1, 3, bf13)
  LOAD_BF(2, 0, bf20) LOAD_BF(2, 1, bf21) LOAD_BF(2, 2, bf22) LOAD_BF(2, 3, bf23)
  LOAD_BF(3, 0, bf30) LOAD_BF(3, 1, bf31) LOAD_BF(3, 2, bf32) LOAD_BF(3, 3, bf33)
#undef LOAD_BF

  __shared__ unsigned short hbuf[2][128];   // h as bf16, double-buffered
  if (tid < 128) { hbuf[0][tid] = 0; hbuf[1][tid] = 0; }
  __syncthreads();

  const size_t base = (size_t)b * 512;
  const int tstep = dir ? -1 : 1;
  const int t0 = dir ? 511 : 0;
  const unsigned short* prow = pre + base * 512 + cell * 4;         // + t*512
  unsigned short* orow = (unsigned short*)out + base * 256 + off + cell;  // + t*256

  int cur = 0;
  float cst = 0.f;
  f32x4 acc0 = {0.f, 0.f, 0.f, 0.f};
  f32x4 acc1 = acc0, acc2 = acc0, acc3 = acc0;

#define LSTM_STEP(P, HOUT)                                                  \
  {                                                                         \
    const unsigned short* hb = hbuf[cur];                                   \
    short8v a0 = *(const short8v*)(hb +  0 + kg * 8);                       \
    short8v a1 = *(const short8v*)(hb + 32 + kg * 8);                       \
    short8v a2 = *(const short8v*)(hb + 64 + kg * 8);                       \
    short8v a3 = *(const short8v*)(hb + 96 + kg * 8);                       \
    acc0[0] = bf2f(P[0]); acc1[0] = bf2f(P[1]);                             \
    acc2[0] = bf2f(P[2]); acc3[0] = bf2f(P[3]);                             \
    acc0 = __builtin_amdgcn_mfma_f32_16x16x32_bf16(a0, bf00, acc0, 0, 0, 0);\
    acc1 = __builtin_amdgcn_mfma_f32_16x16x32_bf16(a0, bf10, acc1, 0, 0, 0);\
    acc2 = __builtin_amdgcn_mfma_f32_16x16x32_bf16(a0, bf20, acc2, 0, 0, 0);\
    acc3 = __builtin_amdgcn_mfma_f32_16x16x32_bf16(a0, bf30, acc3, 0, 0, 0);\
    acc0 = __builtin_amdgcn_mfma_f32_16x16x32_bf16(a1, bf01, acc0, 0, 0, 0);\
    acc1 = __builtin_amdgcn_mfma_f32_16x16x32_bf16(a1, bf11, acc1, 0, 0, 0);\
    acc2 = __builtin_amdgcn_mfma_f32_16x16x32_bf16(a1, bf21, acc2, 0, 0, 0);\
    acc3 = __builtin_amdgcn_mfma_f32_16x16x32_bf16(a1, bf31, acc3, 0, 0, 0);\
    acc0 = __builtin_amdgcn_mfma_f32_16x16x32_bf16(a2, bf02, acc0, 0, 0, 0);\
    acc1 = __builtin_amdgcn_mfma_f32_16x16x32_bf16(a2, bf12, acc1, 0, 0, 0);\
    acc2 = __builtin_amdgcn_mfma_f32_16x16x32_bf16(a2, bf22, acc2, 0, 0, 0);\
    acc3 = __builtin_amdgcn_mfma_f32_16x16x32_bf16(a2, bf32, acc3, 0, 0, 0);\
    acc0 = __builtin_amdgcn_mfma_f32_16x16x32_bf16(a3, bf03, acc0, 0, 0, 0);\
    acc1 = __builtin_amdgcn_mfma_f32_16x16x32_bf16(a3, bf13, acc1, 0, 0, 0);\
    acc2 = __builtin_amdgcn_mfma_f32_16x16x32_bf16(a3, bf23, acc2, 0, 0, 0);\
    acc3 = __builtin_amdgcn_mfma_f32_16x16x32_bf16(a3, bf33, acc3, 0, 0, 0);\
    float gi_ = fsig(acc0[0]);                                              \
    float gf_ = fsig(acc1[0]);                                              \
    float gg_ = ftanh(acc2[0]);                                             \
    float go_ = fsig(acc3[0]);                                              \
    cst = gf_ * cst + gi_ * gg_;                                            \
    float hv = go_ * ftanh(cst);                                            \
    HOUT = f2bf(hv);                                                        \
    if (lane < 16) hbuf[cur ^ 1][cell] = HOUT;                              \
    __syncthreads();                                                        \
    cur ^= 1;                                                               \
  }

  for (int chunk = 0; chunk < 64; ++chunk) {
    const int tb = t0 + chunk * 8 * tstep;   // first t of this chunk
    // issue all 8 pre loads (independent, in flight together; drained once
    // by step 0's __syncthreads)
    ushort4v p0 = *(const ushort4v*)(prow + (size_t)(tb)             * 512);
    ushort4v p1 = *(const ushort4v*)(prow + (size_t)(tb + 1 * tstep) * 512);
    ushort4v p2 = *(const ushort4v*)(prow + (size_t)(tb + 2 * tstep) * 512);
    ushort4v p3 = *(const ushort4v*)(prow + (size_t)(tb + 3 * tstep) * 512);
    ushort4v p4 = *(const ushort4v*)(prow + (size_t)(tb + 4 * tstep) * 512);
    ushort4v p5 = *(const ushort4v*)(prow + (size_t)(tb + 5 * tstep) * 512);
    ushort4v p6 = *(const ushort4v*)(prow + (size_t)(tb + 6 * tstep) * 512);
    ushort4v p7 = *(const ushort4v*)(prow + (size_t)(tb + 7 * tstep) * 512);
    unsigned short h0, h1, h2, h3, h4, h5, h6, h7;
    LSTM_STEP(p0, h0)
    LSTM_STEP(p1, h1)
    LSTM_STEP(p2, h2)
    LSTM_STEP(p3, h3)
    LSTM_STEP(p4, h4)
    LSTM_STEP(p5, h5)
    LSTM_STEP(p6, h6)
    LSTM_STEP(p7, h7)
    if (lane < 16) {
      orow[(size_t)(tb)             * 256] = h0;
      orow[(size_t)(tb + 1 * tstep) * 256] = h1;
      orow[(size_t)(tb + 2 * tstep) * 256] = h2;
      orow[(size_t)(tb + 3 * tstep) * 256] = h3;
      orow[(size_t)(tb + 4 * tstep) * 256] = h4;
      orow[(size_t)(tb + 5 * tstep) * 256] = h5;
      orow[(size_t)(tb + 6 * tstep) * 256] = h6;
      orow[(size_t)(tb + 7 * tstep) * 256] = h7;
    }
  }
#undef LSTM_STEP
}

// ---------------- logits: z[row] = gz[row] + m_row(bf16) . W[1024:1280] + bias ----
// grid 8192, block 256 (wave per row)
__global__ __launch_bounds__(256) void logits_kernel(
    const __hip_bfloat16* __restrict__ m, const float* __restrict__ W,
    const float* __restrict__ bias, const float* __restrict__ gz,
    float* __restrict__ z)
{
  const int row = blockIdx.x * 4 + (threadIdx.x >> 6);
  const int lane = threadIdx.x & 63;
  const unsigned short* mrow = (const unsigned short*)m + (size_t)row * 256;
  float acc = 0.f;
  #pragma unroll
  for (int i = 0; i < 4; ++i) acc += bf2f(mrow[lane + 64 * i]) * W[1024 + lane + 64 * i];
  #pragma unroll
  for (int off = 32; off; off >>= 1) acc += __shfl_xor(acc, off);
  if (lane == 0) z[row] = acc + gz[row] + bias[0];
}

// ---------------- softmax over t ----------------
// grid 64, block 512
__global__ __launch_bounds__(512) void softmax_t_kernel(
    const float* __restrict__ z, float* __restrict__ p)
{
  const int b = blockIdx.x, t = threadIdx.x;
  __shared__ float red[8], red2[8];
  float v = z[(size_t)b * 512 + t];
  float m = v;
  #pragma unroll
  for (int off = 32; off; off >>= 1) m = fmaxf(m, __shfl_xor(m, off));
  if ((t & 63) == 0) red[t >> 6] = m;
  __syncthreads();
  float M = red[0];
  #pragma unroll
  for (int i = 1; i < 8; ++i) M = fmaxf(M, red[i]);
  float e = expf(v - M);
  float s = e;
  #pragma unroll
  for (int off = 32; off; off >>= 1) s += __shfl_xor(s, off);
  if ((t & 63) == 0) red2[t >> 6] = s;
  __syncthreads();
  float S = red2[0];
  #pragma unroll
  for (int i = 1; i < 8; ++i) S += red2[i];
  p[(size_t)b * 512 + t] = e / S;
}

extern "C" void kernel_launch(void* const* d_in, const int* in_sizes, int n_in,
                              void* d_out, int out_size, void* d_ws, size_t ws_size,
                              hipStream_t stream)
{
  const float* c   = (const float*)d_in[0];
  const float* q   = (const float*)d_in[1];
  const float* wc  = (const float*)d_in[2];
  const float* bc  = (const float*)d_in[3];
  const float* wq  = (const float*)d_in[4];
  const float* bq  = (const float*)d_in[5];
  const float* wcq = (const float*)d_in[6];
  const float* bcq = (const float*)d_in[7];
  const float* l1f_Wih = (const float*)d_in[8];
  const float* l1f_Whh = (const float*)d_in[9];
  const float* l1f_bih = (const float*)d_in[10];
  const float* l1f_bhh = (const float*)d_in[11];
  const float* l1b_Wih = (const float*)d_in[12];
  const float* l1b_Whh = (const float*)d_in[13];
  const float* l1b_bih = (const float*)d_in[14];
  const float* l1b_bhh = (const float*)d_in[15];
  const float* l2f_Wih = (const float*)d_in[16];
  const float* l2f_Whh = (const float*)d_in[17];
  const float* l2f_bih = (const float*)d_in[18];
  const float* l2f_bhh = (const float*)d_in[19];
  const float* l2b_Wih = (const float*)d_in[20];
  const float* l2b_Whh = (const float*)d_in[21];
  const float* l2b_bih = (const float*)d_in[22];
  const float* l2b_bhh = (const float*)d_in[23];
  const float* W0 = (const float*)d_in[24];
  const float* b0 = (const float*)d_in[25];
  const float* W1 = (const float*)d_in[26];
  const float* b1 = (const float*)d_in[27];

  const size_t required = 134742016u;
  if (ws_size < required) return;

  char* wsb = (char*)d_ws;
  __hip_bfloat16* gbf = (__hip_bfloat16*)wsb;                  // 67,108,864 B
  __hip_bfloat16* m   = (__hip_bfloat16*)wsb;                  // alias (g dead after gemm1)
  __hip_bfloat16* m2  = (__hip_bfloat16*)(wsb + 33554432);     // alias
  __hip_bfloat16* pref = (__hip_bfloat16*)(wsb + 67108864);    // 33,554,432 B
  __hip_bfloat16* preb = (__hip_bfloat16*)(wsb + 100663296);   // 33,554,432 B
  float* gz0  = (float*)(wsb + 134217728);
  float* gz1  = gz0 + 32768;
  float* smax = gz1 + 32768;
  float* z    = smax + 32768;
  float* p1   = (float*)d_out;
  float* p2   = p1 + 32768;

  attn_kernel<<<dim3(64, 4), 256, 0, stream>>>(c, q, wc, bc, wq, bq, wcq, bcq,
                                               W0, W1, gbf, smax, gz0, gz1);
  batt_kernel<<<64, 256, 0, stream>>>(c, smax, W0, W1, gbf, gz0, gz1);

  gemm_mfma_kernel<<<dim3(256, 4), 256, 0, stream>>>(gbf, l1f_Wih, l1f_bih, l1f_bhh, pref, 1024, 512);
  gemm_mfma_kernel<<<dim3(256, 4), 256, 0, stream>>>(gbf, l1b_Wih, l1b_bih, l1b_bhh, preb, 1024, 512);
  lstm_kernel<<<dim3(64, 2), 512, 0, stream>>>(pref, preb, l1f_Whh, l1b_Whh, m);

  logits_kernel<<<8192, 256, 0, stream>>>(m, W0, b0, gz0, z);
  softmax_t_kernel<<<64, 512, 0, stream>>>(z, p1);

  gemm_mfma_kernel<<<dim3(256, 4), 256, 0, stream>>>(m, l2f_Wih, l2f_bih, l2f_bhh, pref, 256, 512);
  gemm_mfma_kernel<<<dim3(256, 4), 256, 0, stream>>>(m, l2b_Wih, l2b_bih, l2b_bhh, preb, 256, 512);
  lstm_kernel<<<dim3(64, 2), 512, 0, stream>>>(pref, preb, l2f_Whh, l2b_Whh, m2);

  logits_kernel<<<8192, 256, 0, stream>>>(m2, W1, b1, gz1, z);
  softmax_t_kernel<<<64, 512, 0, stream>>>(z, p2);
}